// Round 5
// baseline (395.696 us; speedup 1.0000x reference)
//
#include <hip/hip_runtime.h>
#include <math.h>

static constexpr int K = 512;
static constexpr int D = 256;
static constexpr float ALPHA = 0.99f;
static constexpr float EPSF  = 2.2204460492503131e-16f;
static constexpr int NB = 512;            // grid size; co-residency capacity is 1024 (2x slack)

typedef __bf16 bf16x8 __attribute__((ext_vector_type(8)));
typedef float floatx4 __attribute__((ext_vector_type(4)));
typedef unsigned long long u64;

// ordered-float encoding: monotone map float -> u32 (smaller float => smaller u32)
__device__ __forceinline__ unsigned int f2o(float f) {
  unsigned int u = __float_as_uint(f);
  return (u & 0x80000000u) ? ~u : (u | 0x80000000u);
}

__device__ __forceinline__ u64 umin64(u64 a, u64 b) { return a < b ? a : b; }

// manual grid barrier: device-scope atomic counter + agent fences (buffer_wbl2/inv).
// Safe because all NB blocks are co-resident (see launch_bounds / LDS math above).
__device__ __forceinline__ void gbar(unsigned int* c) {
  __syncthreads();
  if (threadIdx.x == 0) {
    __threadfence();   // release: flush this block's writes device-wide
    __hip_atomic_fetch_add(c, 1u, __ATOMIC_ACQ_REL, __HIP_MEMORY_SCOPE_AGENT);
    while (__hip_atomic_load(c, __ATOMIC_ACQUIRE, __HIP_MEMORY_SCOPE_AGENT) < (unsigned)NB)
      __builtin_amdgcn_s_sleep(2);
    __threadfence();   // acquire: invalidate stale lines before post-barrier reads
  }
  __syncthreads();
}

// ===== one persistent kernel, 3 stages separated by manual grid barriers =====
// Stage 1: sim1 (1024 jobs of 64 rows) -> simbuf, p0[ b*8+s ], Fbf (bf16 cast)
// Stage 2: jobs 0..511 = sim2 quarters -> p1; jobs 512..1791 = gram tiles -> Dgp
// Stage 3: final propagation (1024 jobs of 64 rows) -> out
__global__ __launch_bounds__(256, 4) void mega_kernel(
    const float* __restrict__ F, const float* __restrict__ Q,
    __bf16* __restrict__ Fbf, float* __restrict__ simbuf,
    u64* __restrict__ p0, u64* __restrict__ p1,
    float* __restrict__ Dgp, float* __restrict__ out,
    unsigned int* __restrict__ bar)
{
  __shared__ __align__(16) unsigned char smem[36864];
  const int g = blockIdx.x;
  const int t = threadIdx.x;
  const int wave = t >> 6, lane = t & 63;
  const int quad = lane >> 4, l15 = lane & 15;
  const int sub = lane >> 4, cg = lane & 15;

  // ---------------- Stage 1: sim1 + bf16 conversion (jobs g, g+512) ----------------
  for (int j = g; j < 1024; j += NB) {
    __syncthreads();
    const int b = j >> 3, s = j & 7;
    const int r0 = s * 64;
    const float* Fb = F + (size_t)b * (K * D);
    __bf16* Fbb = Fbf + (size_t)b * (K * D);
    float* qs = (float*)smem;
    u64* wred = (u64*)(smem + 1024);
    qs[t] = Q[(size_t)b * D + t];
    __syncthreads();

    u64 best = ~0ULL;
    #pragma unroll
    for (int pass = 0; pass < 4; ++pass) {
      const int r = r0 + pass * 16 + wave * 4 + sub;
      const float* fr = Fb + (size_t)r * D;
      float p = 0.f;
      #pragma unroll
      for (int q = 0; q < 2; ++q) {
        const int c = q * 128 + cg * 8;
        const float4 f0 = *(const float4*)(fr + c);
        const float4 f1 = *(const float4*)(fr + c + 4);
        const float4 q0 = *(const float4*)(qs + c);
        const float4 q1 = *(const float4*)(qs + c + 4);
        p += f0.x*q0.x + f0.y*q0.y + f0.z*q0.z + f0.w*q0.w
           + f1.x*q1.x + f1.y*q1.y + f1.z*q1.z + f1.w*q1.w;
        bf16x8 h;
        h[0] = (__bf16)f0.x; h[1] = (__bf16)f0.y; h[2] = (__bf16)f0.z; h[3] = (__bf16)f0.w;
        h[4] = (__bf16)f1.x; h[5] = (__bf16)f1.y; h[6] = (__bf16)f1.z; h[7] = (__bf16)f1.w;
        *(bf16x8*)(Fbb + (size_t)r * D + c) = h;
      }
      p += __shfl_xor(p, 1, 64); p += __shfl_xor(p, 2, 64);
      p += __shfl_xor(p, 4, 64); p += __shfl_xor(p, 8, 64);
      if (cg == 0) {
        simbuf[(size_t)b * K + r] = p;
        best = umin64(best, ((u64)f2o(p) << 32) | (unsigned int)r);
      }
    }
    best = umin64(best, __shfl_xor(best, 16, 64));
    best = umin64(best, __shfl_xor(best, 32, 64));
    if (lane == 0) wred[wave] = best;
    __syncthreads();
    if (t == 0)
      p0[b * 8 + s] = umin64(umin64(wred[0], wred[1]), umin64(wred[2], wred[3]));
  }

  gbar(&bar[0]);

  // ---------------- Stage 2: sim2 (jobs 0..511) + gram tiles (jobs 512..1791) -------
  for (int j = g; j < 1792; j += NB) {
    __syncthreads();
    if (j < 512) {
      // ---- sim2 quarter (fp32-exact): 128 rows ----
      const int b = j & 127, s = j >> 7;
      const int r0 = s * 128;
      const float* Fb = F + (size_t)b * (K * D);
      float* qs = (float*)smem;
      u64* wred = (u64*)(smem + 1024);

      u64 e0 = p0[b * 8];
      #pragma unroll
      for (int i = 1; i < 8; ++i) e0 = umin64(e0, p0[b * 8 + i]);
      const int a0 = (int)(e0 & 0xffffffffu);

      qs[t] = Fb[(size_t)a0 * D + t];
      __syncthreads();

      u64 best = ~0ULL;
      #pragma unroll
      for (int pass = 0; pass < 8; ++pass) {
        const int r = r0 + pass * 16 + wave * 4 + sub;
        const float* fr = Fb + (size_t)r * D;
        float p = 0.f;
        #pragma unroll
        for (int q = 0; q < 2; ++q) {
          const int c = q * 128 + cg * 8;
          const float4 f0 = *(const float4*)(fr + c);
          const float4 f1 = *(const float4*)(fr + c + 4);
          const float4 q0 = *(const float4*)(qs + c);
          const float4 q1 = *(const float4*)(qs + c + 4);
          p += f0.x*q0.x + f0.y*q0.y + f0.z*q0.z + f0.w*q0.w
             + f1.x*q1.x + f1.y*q1.y + f1.z*q1.z + f1.w*q1.w;
        }
        p += __shfl_xor(p, 1, 64); p += __shfl_xor(p, 2, 64);
        p += __shfl_xor(p, 4, 64); p += __shfl_xor(p, 8, 64);
        if (cg == 0) {
          const float m = fmaxf(simbuf[(size_t)b * K + r], p);
          best = umin64(best, ((u64)f2o(m) << 32) | (unsigned int)r);
        }
      }
      best = umin64(best, __shfl_xor(best, 16, 64));
      best = umin64(best, __shfl_xor(best, 32, 64));
      if (lane == 0) wred[wave] = best;
      __syncthreads();
      if (t == 0)
        p1[b * 4 + s] = umin64(umin64(wred[0], wred[1]), umin64(wred[2], wred[3]));
    } else {
      // ---- gram tile: 128 x 128 (proven 256-thread body) ----
      const int T = j - 512;
      const int b = T & 127;
      const int tid = T >> 7;                 // 0..9
      static constexpr int TI[10] = {0,1,1,2,2,2,3,3,3,3};
      static constexpr int TJ[10] = {0,0,1,0,1,2,0,1,2,3};
      const int ti = TI[tid], tj = TJ[tid];
      const int r0 = ti * 128, c0 = tj * 128;
      const bool diag = (ti == tj);
      const __bf16* Fb = Fbf + (size_t)b * (K * D);
      __bf16 (*Asb)[72] = (__bf16(*)[72])smem;            // 128 x 72 bf16
      __bf16 (*Bsb)[72] = diag ? Asb : (__bf16(*)[72])(smem + 18432);
      const int srow = t >> 1, skh = (t & 1) * 32;

      floatx4 acc[2][8];
      #pragma unroll
      for (int i = 0; i < 2; ++i)
        #pragma unroll
        for (int n = 0; n < 8; ++n) acc[i][n] = (floatx4){0.f, 0.f, 0.f, 0.f};

      for (int kk = 0; kk < D; kk += 64) {
        __syncthreads();
        {
          const __bf16* sa = Fb + (size_t)(r0 + srow) * D + kk + skh;
          *(uint4*)&Asb[srow][skh +  0] = *(const uint4*)(sa +  0);
          *(uint4*)&Asb[srow][skh +  8] = *(const uint4*)(sa +  8);
          *(uint4*)&Asb[srow][skh + 16] = *(const uint4*)(sa + 16);
          *(uint4*)&Asb[srow][skh + 24] = *(const uint4*)(sa + 24);
          if (!diag) {
            const __bf16* sb = Fb + (size_t)(c0 + srow) * D + kk + skh;
            *(uint4*)&Bsb[srow][skh +  0] = *(const uint4*)(sb +  0);
            *(uint4*)&Bsb[srow][skh +  8] = *(const uint4*)(sb +  8);
            *(uint4*)&Bsb[srow][skh + 16] = *(const uint4*)(sb + 16);
            *(uint4*)&Bsb[srow][skh + 24] = *(const uint4*)(sb + 24);
          }
        }
        __syncthreads();
        #pragma unroll
        for (int k2 = 0; k2 < 64; k2 += 32) {
          bf16x8 af[2], bfr[8];
          #pragma unroll
          for (int tm = 0; tm < 2; ++tm)
            af[tm] = *(bf16x8*)&Asb[wave * 32 + tm * 16 + l15][k2 + quad * 8];
          #pragma unroll
          for (int tn = 0; tn < 8; ++tn)
            bfr[tn] = *(bf16x8*)&Bsb[tn * 16 + l15][k2 + quad * 8];
          #pragma unroll
          for (int tm = 0; tm < 2; ++tm)
            #pragma unroll
            for (int tn = 0; tn < 8; ++tn)
              acc[tm][tn] = __builtin_amdgcn_mfma_f32_16x16x32_bf16(af[tm], bfr[tn], acc[tm][tn], 0, 0, 0);
        }
      }

      // epilogue: exp (+zero diag on diag tiles), row sums + col sums
      float rs[8] = {0.f};
      float cs[8] = {0.f};
      #pragma unroll
      for (int tm = 0; tm < 2; ++tm) {
        const int lrb = wave * 32 + tm * 16 + quad * 4;
        #pragma unroll
        for (int tn = 0; tn < 8; ++tn) {
          const int lc = tn * 16 + l15;
          #pragma unroll
          for (int r = 0; r < 4; ++r) {
            float wv = __expf(acc[tm][tn][r]);
            if (diag && (lrb + r) == lc) wv = 0.f;
            rs[tm * 4 + r] += wv;
            cs[tn] += wv;
          }
        }
      }
      // row sums -> slot tj
      #pragma unroll
      for (int s = 0; s < 8; ++s) {
        float v = rs[s];
        v += __shfl_xor(v, 1, 64); v += __shfl_xor(v, 2, 64);
        v += __shfl_xor(v, 4, 64); v += __shfl_xor(v, 8, 64);
        if (l15 == 0) {
          const int r = r0 + wave * 32 + (s >> 2) * 16 + quad * 4 + (s & 3);
          Dgp[(size_t)tj * (128 * K) + (size_t)b * K + r] = v;
        }
      }
      // col sums -> slot ti (off-diag tiles only)
      if (!diag) {
        #pragma unroll
        for (int tn = 0; tn < 8; ++tn) {
          cs[tn] += __shfl_xor(cs[tn], 16, 64);
          cs[tn] += __shfl_xor(cs[tn], 32, 64);
        }
        __syncthreads();                       // done with Asb/Bsb
        float* csum = (float*)smem;            // 4 x 128 floats
        if (lane < 16) {
          #pragma unroll
          for (int tn = 0; tn < 8; ++tn)
            csum[wave * 128 + tn * 16 + l15] = cs[tn];
        }
        __syncthreads();
        if (t < 128) {
          const float s = csum[t] + csum[128 + t] + csum[256 + t] + csum[384 + t];
          Dgp[(size_t)ti * (128 * K) + (size_t)b * K + c0 + t] = s;
        }
      }
    }
  }

  gbar(&bar[1]);

  // ---------------- Stage 3: final propagation (jobs g, g+512; 64 rows each) --------
  for (int j = g; j < 1024; j += NB) {
    __syncthreads();
    const int b = j >> 3, s = j & 7;
    const int r0 = s * 64;
    const float* Fb = F + (size_t)b * (K * D);
    const __bf16* Fbb = Fbf + (size_t)b * (K * D);
    float* qa     = (float*)smem;                 // 256 f
    float* qb     = qa + 256;                     // 256 f
    float* dinv_s = qb + 256;                     // 512 f
    float* sqd_s  = dinv_s + 512;                 // 512 f
    float* red    = sqd_s + 512;                  // 4 f

    u64 e0 = p0[b * 8];
    #pragma unroll
    for (int i = 1; i < 8; ++i) e0 = umin64(e0, p0[b * 8 + i]);
    u64 e1 = p1[b * 4];
    #pragma unroll
    for (int i = 1; i < 4; ++i) e1 = umin64(e1, p1[b * 4 + i]);
    const int a0 = (int)(e0 & 0xffffffffu);
    const int a1 = (int)(e1 & 0xffffffffu);

    qa[t] = Fb[(size_t)a0 * D + t];
    qb[t] = Fb[(size_t)a1 * D + t];
    float dsum = 0.f;
    for (int k = t; k < K; k += 256) {
      const size_t o = (size_t)b * K + k;
      const float d = Dgp[o] + Dgp[(size_t)128 * K + o]
                    + Dgp[(size_t)2 * 128 * K + o] + Dgp[(size_t)3 * 128 * K + o];
      dinv_s[k] = 1.0f / sqrtf(d + EPSF);
      sqd_s[k] = sqrtf(d);
      dsum += d;
    }
    #pragma unroll
    for (int off = 32; off >= 1; off >>= 1) dsum += __shfl_down(dsum, off, 64);
    if (lane == 0) red[wave] = dsum;
    __syncthreads();
    const float vn = 1.0f / sqrtf(red[0] + red[1] + red[2] + red[3]);
    const float s0 = vn * sqd_s[a0], s1 = vn * sqd_s[a1];   // v[a0], v[a1]
    const float dia0 = dinv_s[a0], dia1 = dinv_s[a1];
    const float c99 = ALPHA / (1.0f - ALPHA);

    float2* ob = (float2*)(out + (size_t)b * K * 2);

    #pragma unroll
    for (int pass = 0; pass < 4; ++pass) {
      const int r = r0 + pass * 16 + wave * 4 + sub;
      const __bf16* fr = Fbb + (size_t)r * D;
      float pa = 0.f, pb = 0.f;
      #pragma unroll
      for (int q = 0; q < 2; ++q) {
        const int c = q * 128 + cg * 8;
        const uint4 wv = *(const uint4*)(fr + c);
        const float4 a0v = *(const float4*)(qa + c);
        const float4 a1v = *(const float4*)(qa + c + 4);
        const float4 b0v = *(const float4*)(qb + c);
        const float4 b1v = *(const float4*)(qb + c + 4);
        const float w0 = __uint_as_float(wv.x << 16);
        const float w1 = __uint_as_float(wv.x & 0xffff0000u);
        const float w2 = __uint_as_float(wv.y << 16);
        const float w3 = __uint_as_float(wv.y & 0xffff0000u);
        const float w4 = __uint_as_float(wv.z << 16);
        const float w5 = __uint_as_float(wv.z & 0xffff0000u);
        const float w6 = __uint_as_float(wv.w << 16);
        const float w7 = __uint_as_float(wv.w & 0xffff0000u);
        pa += w0*a0v.x + w1*a0v.y + w2*a0v.z + w3*a0v.w
            + w4*a1v.x + w5*a1v.y + w6*a1v.z + w7*a1v.w;
        pb += w0*b0v.x + w1*b0v.y + w2*b0v.z + w3*b0v.w
            + w4*b1v.x + w5*b1v.y + w6*b1v.z + w7*b1v.w;
      }
      pa += __shfl_xor(pa, 1, 64); pa += __shfl_xor(pa, 2, 64);
      pa += __shfl_xor(pa, 4, 64); pa += __shfl_xor(pa, 8, 64);
      pb += __shfl_xor(pb, 1, 64); pb += __shfl_xor(pb, 2, 64);
      pb += __shfl_xor(pb, 4, 64); pb += __shfl_xor(pb, 8, 64);
      if (cg == 0) {
        const float q0 = ((r == a0) ? 0.f : __expf(pa)) * dia0;
        const float q1 = ((r == a1) ? 0.f : __expf(pb)) * dia1;
        const float di = dinv_s[r];
        const float vr = vn * sqd_s[r];                      // v[r]
        const float w0n = ALPHA * (di * q0 - vr * s0);
        const float w1n = ALPHA * (di * q1 - vr * s1);
        float2 o;
        o.x = ((r == a0) ? 1.f : 0.f) + w0n + c99 * s0 * vr;
        o.y = ((r == a1) ? 1.f : 0.f) + w1n + c99 * s1 * vr;
        ob[r] = o;
      }
    }
  }
}

// ==========================================================================
extern "C" void kernel_launch(void* const* d_in, const int* in_sizes, int n_in,
                              void* d_out, int out_size, void* d_ws, size_t ws_size,
                              hipStream_t stream) {
  const float* F = (const float*)d_in[0];   // [B,K,D]
  const float* Q = (const float*)d_in[1];   // [B,D]
  float* out = (float*)d_out;               // [B,K,2]
  const int B = 128;

  __bf16* Fbf = (__bf16*)d_ws;                           // B*K*D bf16 (33.5 MB)
  float* Dgp  = (float*)(Fbf + (size_t)B * K * D);       // 4*B*K (partial degrees)
  float* simb = Dgp + (size_t)4 * B * K;                 // B*K
  u64*   p0   = (u64*)(simb + (size_t)B * K);            // B*8
  u64*   p1   = p0 + (size_t)B * 8;                      // B*4
  unsigned int* bar = (unsigned int*)(p1 + (size_t)B * 4);  // 2 counters

  hipMemsetAsync(bar, 0, 64, stream);
  mega_kernel<<<NB, 256, 0, stream>>>(F, Q, Fbf, simb, p0, p1, Dgp, out, bar);
}

// Round 6
// 371.819 us; speedup vs baseline: 1.0642x; 1.0642x over previous
//
#include <hip/hip_runtime.h>
#include <math.h>

static constexpr int K = 512;
static constexpr int D = 256;
static constexpr float ALPHA = 0.99f;
static constexpr float EPSF  = 2.2204460492503131e-16f;

typedef __bf16 bf16x8 __attribute__((ext_vector_type(8)));
typedef float floatx4 __attribute__((ext_vector_type(4)));
typedef unsigned long long u64;

// ordered-float encoding: monotone map float -> u32 (smaller float => smaller u32)
__device__ __forceinline__ unsigned int f2o(float f) {
  unsigned int u = __float_as_uint(f);
  return (u & 0x80000000u) ? ~u : (u | 0x80000000u);
}

__device__ __forceinline__ u64 umin64(u64 a, u64 b) { return a < b ? a : b; }

// ---- per-batch dataflow flags (64B stride per batch to avoid line sharing) ----
// release: __syncthreads() has drained all waves' stores to L2; thread0's
// __threadfence() (buffer_wbl2) makes them device-visible; then agent-scope add.
__device__ __forceinline__ void signal_flag(unsigned int* f) {
  __syncthreads();
  if (threadIdx.x == 0) {
    __threadfence();
    __hip_atomic_fetch_add(f, 1u, __ATOMIC_RELEASE, __HIP_MEMORY_SCOPE_AGENT);
  }
}
// acquire: relaxed spin (no per-iter cache inv), one full fence on exit.
__device__ __forceinline__ void wait_flag(const unsigned int* f, unsigned int tgt) {
  if (threadIdx.x == 0) {
    while (__hip_atomic_load(f, __ATOMIC_RELAXED, __HIP_MEMORY_SCOPE_AGENT) < tgt)
      __builtin_amdgcn_s_sleep(8);
    __threadfence();
  }
  __syncthreads();
}
__device__ __forceinline__ void wait_flag2(const unsigned int* f1, unsigned int t1,
                                           const unsigned int* f2, unsigned int t2) {
  if (threadIdx.x == 0) {
    while (__hip_atomic_load(f1, __ATOMIC_RELAXED, __HIP_MEMORY_SCOPE_AGENT) < t1 ||
           __hip_atomic_load(f2, __ATOMIC_RELAXED, __HIP_MEMORY_SCOPE_AGENT) < t2)
      __builtin_amdgcn_s_sleep(8);
    __threadfence();
  }
  __syncthreads();
}

// ===== single-dispatch per-batch pipeline =====
// blockIdx  [0,1024): sim1  (b = bid>>3, 64 rows)      -> simbuf, p0, Fbf; ++done1[b]
// [1024,1536): sim2 quarter (waits done1[b]==8)        -> p1;              ++done2[b]
// [1536,2816): gram tile    (waits done1[b]==8)        -> Dgp;             ++doneg[b]
// [2816,3840): final strip  (waits doneg[b]==10 && done2[b]==4) -> out
__global__ __launch_bounds__(256, 4) void pipe_kernel(
    const float* __restrict__ F, const float* __restrict__ Q,
    __bf16* __restrict__ Fbf, float* __restrict__ simbuf,
    u64* __restrict__ p0, u64* __restrict__ p1,
    float* __restrict__ Dgp, float* __restrict__ out,
    unsigned int* __restrict__ flags)
{
  __shared__ __align__(16) unsigned char smem[36864];
  const int bid = blockIdx.x;
  const int t = threadIdx.x;
  const int wave = t >> 6, lane = t & 63;
  const int quad = lane >> 4, l15 = lane & 15;
  const int sub = quad, cg = l15;

  if (bid < 1024) {
    // ---------------- sim1: 64 rows, dot with q + bf16 emit ----------------
    const int b = bid >> 3, s = bid & 7;
    const int r0 = s * 64;
    const float* Fb = F + (size_t)b * (K * D);
    __bf16* Fbb = Fbf + (size_t)b * (K * D);
    float* qs = (float*)smem;
    u64* wred = (u64*)(smem + 1024);
    qs[t] = Q[(size_t)b * D + t];
    __syncthreads();

    u64 best = ~0ULL;
    #pragma unroll
    for (int pass = 0; pass < 4; ++pass) {
      const int r = r0 + pass * 16 + wave * 4 + sub;
      const float* fr = Fb + (size_t)r * D;
      float p = 0.f;
      #pragma unroll
      for (int q = 0; q < 2; ++q) {
        const int c = q * 128 + cg * 8;
        const float4 f0 = *(const float4*)(fr + c);
        const float4 f1 = *(const float4*)(fr + c + 4);
        const float4 q0 = *(const float4*)(qs + c);
        const float4 q1 = *(const float4*)(qs + c + 4);
        p += f0.x*q0.x + f0.y*q0.y + f0.z*q0.z + f0.w*q0.w
           + f1.x*q1.x + f1.y*q1.y + f1.z*q1.z + f1.w*q1.w;
        bf16x8 h;
        h[0] = (__bf16)f0.x; h[1] = (__bf16)f0.y; h[2] = (__bf16)f0.z; h[3] = (__bf16)f0.w;
        h[4] = (__bf16)f1.x; h[5] = (__bf16)f1.y; h[6] = (__bf16)f1.z; h[7] = (__bf16)f1.w;
        *(bf16x8*)(Fbb + (size_t)r * D + c) = h;
      }
      p += __shfl_xor(p, 1, 64); p += __shfl_xor(p, 2, 64);
      p += __shfl_xor(p, 4, 64); p += __shfl_xor(p, 8, 64);
      if (cg == 0) {
        simbuf[(size_t)b * K + r] = p;
        best = umin64(best, ((u64)f2o(p) << 32) | (unsigned int)r);
      }
    }
    best = umin64(best, __shfl_xor(best, 16, 64));
    best = umin64(best, __shfl_xor(best, 32, 64));
    if (lane == 0) wred[wave] = best;
    __syncthreads();
    if (t == 0)
      p0[b * 8 + s] = umin64(umin64(wred[0], wred[1]), umin64(wred[2], wred[3]));
    signal_flag(&flags[b * 16]);                          // done1[b]
  } else if (bid < 1536) {
    // ---------------- sim2 quarter (fp32-exact): 128 rows ----------------
    const int u = bid - 1024;
    const int b = u & 127, s = u >> 7;
    const int r0 = s * 128;
    const float* Fb = F + (size_t)b * (K * D);
    float* qs = (float*)smem;
    u64* wred = (u64*)(smem + 1024);

    wait_flag(&flags[b * 16], 8u);                        // need p0 + simbuf of b

    u64 e0 = p0[b * 8];
    #pragma unroll
    for (int i = 1; i < 8; ++i) e0 = umin64(e0, p0[b * 8 + i]);
    const int a0 = (int)(e0 & 0xffffffffu);

    qs[t] = Fb[(size_t)a0 * D + t];
    __syncthreads();

    u64 best = ~0ULL;
    #pragma unroll
    for (int pass = 0; pass < 8; ++pass) {
      const int r = r0 + pass * 16 + wave * 4 + sub;
      const float* fr = Fb + (size_t)r * D;
      float p = 0.f;
      #pragma unroll
      for (int q = 0; q < 2; ++q) {
        const int c = q * 128 + cg * 8;
        const float4 f0 = *(const float4*)(fr + c);
        const float4 f1 = *(const float4*)(fr + c + 4);
        const float4 q0 = *(const float4*)(qs + c);
        const float4 q1 = *(const float4*)(qs + c + 4);
        p += f0.x*q0.x + f0.y*q0.y + f0.z*q0.z + f0.w*q0.w
           + f1.x*q1.x + f1.y*q1.y + f1.z*q1.z + f1.w*q1.w;
      }
      p += __shfl_xor(p, 1, 64); p += __shfl_xor(p, 2, 64);
      p += __shfl_xor(p, 4, 64); p += __shfl_xor(p, 8, 64);
      if (cg == 0) {
        const float m = fmaxf(simbuf[(size_t)b * K + r], p);
        best = umin64(best, ((u64)f2o(m) << 32) | (unsigned int)r);
      }
    }
    best = umin64(best, __shfl_xor(best, 16, 64));
    best = umin64(best, __shfl_xor(best, 32, 64));
    if (lane == 0) wred[wave] = best;
    __syncthreads();
    if (t == 0)
      p1[b * 4 + s] = umin64(umin64(wred[0], wred[1]), umin64(wred[2], wred[3]));
    signal_flag(&flags[(256 + b) * 16]);                  // done2[b]
  } else if (bid < 2816) {
    // ---------------- gram tile: 128 x 128 (bf16 MFMA) ----------------
    const int T = bid - 1536;
    const int b = T & 127;
    const int tid = T >> 7;                 // 0..9
    static constexpr int TI[10] = {0,1,1,2,2,2,3,3,3,3};
    static constexpr int TJ[10] = {0,0,1,0,1,2,0,1,2,3};
    const int ti = TI[tid], tj = TJ[tid];
    const int r0 = ti * 128, c0 = tj * 128;
    const bool diag = (ti == tj);
    const __bf16* Fb = Fbf + (size_t)b * (K * D);
    __bf16 (*Asb)[72] = (__bf16(*)[72])smem;            // 128 x 72 bf16
    __bf16 (*Bsb)[72] = diag ? Asb : (__bf16(*)[72])(smem + 18432);
    const int srow = t >> 1, skh = (t & 1) * 32;

    wait_flag(&flags[b * 16], 8u);                        // need Fbf of b

    floatx4 acc[2][8];
    #pragma unroll
    for (int i = 0; i < 2; ++i)
      #pragma unroll
      for (int n = 0; n < 8; ++n) acc[i][n] = (floatx4){0.f, 0.f, 0.f, 0.f};

    for (int kk = 0; kk < D; kk += 64) {
      __syncthreads();
      {
        const __bf16* sa = Fb + (size_t)(r0 + srow) * D + kk + skh;
        *(uint4*)&Asb[srow][skh +  0] = *(const uint4*)(sa +  0);
        *(uint4*)&Asb[srow][skh +  8] = *(const uint4*)(sa +  8);
        *(uint4*)&Asb[srow][skh + 16] = *(const uint4*)(sa + 16);
        *(uint4*)&Asb[srow][skh + 24] = *(const uint4*)(sa + 24);
        if (!diag) {
          const __bf16* sb = Fb + (size_t)(c0 + srow) * D + kk + skh;
          *(uint4*)&Bsb[srow][skh +  0] = *(const uint4*)(sb +  0);
          *(uint4*)&Bsb[srow][skh +  8] = *(const uint4*)(sb +  8);
          *(uint4*)&Bsb[srow][skh + 16] = *(const uint4*)(sb + 16);
          *(uint4*)&Bsb[srow][skh + 24] = *(const uint4*)(sb + 24);
        }
      }
      __syncthreads();
      #pragma unroll
      for (int k2 = 0; k2 < 64; k2 += 32) {
        bf16x8 af[2], bfr[8];
        #pragma unroll
        for (int tm = 0; tm < 2; ++tm)
          af[tm] = *(bf16x8*)&Asb[wave * 32 + tm * 16 + l15][k2 + quad * 8];
        #pragma unroll
        for (int tn = 0; tn < 8; ++tn)
          bfr[tn] = *(bf16x8*)&Bsb[tn * 16 + l15][k2 + quad * 8];
        #pragma unroll
        for (int tm = 0; tm < 2; ++tm)
          #pragma unroll
          for (int tn = 0; tn < 8; ++tn)
            acc[tm][tn] = __builtin_amdgcn_mfma_f32_16x16x32_bf16(af[tm], bfr[tn], acc[tm][tn], 0, 0, 0);
      }
    }

    // epilogue: exp (+zero diag on diag tiles), row sums + col sums
    float rs[8] = {0.f};
    float cs[8] = {0.f};
    #pragma unroll
    for (int tm = 0; tm < 2; ++tm) {
      const int lrb = wave * 32 + tm * 16 + quad * 4;
      #pragma unroll
      for (int tn = 0; tn < 8; ++tn) {
        const int lc = tn * 16 + l15;
        #pragma unroll
        for (int r = 0; r < 4; ++r) {
          float wv = __expf(acc[tm][tn][r]);
          if (diag && (lrb + r) == lc) wv = 0.f;
          rs[tm * 4 + r] += wv;
          cs[tn] += wv;
        }
      }
    }
    // row sums -> slot tj
    #pragma unroll
    for (int s = 0; s < 8; ++s) {
      float v = rs[s];
      v += __shfl_xor(v, 1, 64); v += __shfl_xor(v, 2, 64);
      v += __shfl_xor(v, 4, 64); v += __shfl_xor(v, 8, 64);
      if (l15 == 0) {
        const int r = r0 + wave * 32 + (s >> 2) * 16 + quad * 4 + (s & 3);
        Dgp[(size_t)tj * (128 * K) + (size_t)b * K + r] = v;
      }
    }
    // col sums -> slot ti (off-diag tiles only)
    if (!diag) {
      #pragma unroll
      for (int tn = 0; tn < 8; ++tn) {
        cs[tn] += __shfl_xor(cs[tn], 16, 64);
        cs[tn] += __shfl_xor(cs[tn], 32, 64);
      }
      __syncthreads();                       // done with Asb/Bsb
      float* csum = (float*)smem;            // 4 x 128 floats
      if (lane < 16) {
        #pragma unroll
        for (int tn = 0; tn < 8; ++tn)
          csum[wave * 128 + tn * 16 + l15] = cs[tn];
      }
      __syncthreads();
      if (t < 128) {
        const float s = csum[t] + csum[128 + t] + csum[256 + t] + csum[384 + t];
        Dgp[(size_t)ti * (128 * K) + (size_t)b * K + c0 + t] = s;
      }
    }
    signal_flag(&flags[(128 + b) * 16]);                  // doneg[b]
  } else {
    // ---------------- final propagation: 64 rows ----------------
    const int u = bid - 2816;
    const int b = u >> 3, s = u & 7;
    const int r0 = s * 64;
    const float* Fb = F + (size_t)b * (K * D);
    const __bf16* Fbb = Fbf + (size_t)b * (K * D);
    float* qa     = (float*)smem;                 // 256 f
    float* qb     = qa + 256;                     // 256 f
    float* dinv_s = qb + 256;                     // 512 f
    float* sqd_s  = dinv_s + 512;                 // 512 f
    float* red    = sqd_s + 512;                  // 4 f

    wait_flag2(&flags[(128 + b) * 16], 10u,               // all gram tiles of b
               &flags[(256 + b) * 16], 4u);               // all sim2 quarters of b

    u64 e0 = p0[b * 8];
    #pragma unroll
    for (int i = 1; i < 8; ++i) e0 = umin64(e0, p0[b * 8 + i]);
    u64 e1 = p1[b * 4];
    #pragma unroll
    for (int i = 1; i < 4; ++i) e1 = umin64(e1, p1[b * 4 + i]);
    const int a0 = (int)(e0 & 0xffffffffu);
    const int a1 = (int)(e1 & 0xffffffffu);

    qa[t] = Fb[(size_t)a0 * D + t];
    qb[t] = Fb[(size_t)a1 * D + t];
    float dsum = 0.f;
    for (int k = t; k < K; k += 256) {
      const size_t o = (size_t)b * K + k;
      const float d = Dgp[o] + Dgp[(size_t)128 * K + o]
                    + Dgp[(size_t)2 * 128 * K + o] + Dgp[(size_t)3 * 128 * K + o];
      dinv_s[k] = 1.0f / sqrtf(d + EPSF);
      sqd_s[k] = sqrtf(d);
      dsum += d;
    }
    #pragma unroll
    for (int off = 32; off >= 1; off >>= 1) dsum += __shfl_down(dsum, off, 64);
    if (lane == 0) red[wave] = dsum;
    __syncthreads();
    const float vn = 1.0f / sqrtf(red[0] + red[1] + red[2] + red[3]);
    const float s0 = vn * sqd_s[a0], s1 = vn * sqd_s[a1];   // v[a0], v[a1]
    const float dia0 = dinv_s[a0], dia1 = dinv_s[a1];
    const float c99 = ALPHA / (1.0f - ALPHA);

    float2* ob = (float2*)(out + (size_t)b * K * 2);

    #pragma unroll
    for (int pass = 0; pass < 4; ++pass) {
      const int r = r0 + pass * 16 + wave * 4 + sub;
      const __bf16* fr = Fbb + (size_t)r * D;
      float pa = 0.f, pb = 0.f;
      #pragma unroll
      for (int q = 0; q < 2; ++q) {
        const int c = q * 128 + cg * 8;
        const uint4 wv = *(const uint4*)(fr + c);
        const float4 a0v = *(const float4*)(qa + c);
        const float4 a1v = *(const float4*)(qa + c + 4);
        const float4 b0v = *(const float4*)(qb + c);
        const float4 b1v = *(const float4*)(qb + c + 4);
        const float w0 = __uint_as_float(wv.x << 16);
        const float w1 = __uint_as_float(wv.x & 0xffff0000u);
        const float w2 = __uint_as_float(wv.y << 16);
        const float w3 = __uint_as_float(wv.y & 0xffff0000u);
        const float w4 = __uint_as_float(wv.z << 16);
        const float w5 = __uint_as_float(wv.z & 0xffff0000u);
        const float w6 = __uint_as_float(wv.w << 16);
        const float w7 = __uint_as_float(wv.w & 0xffff0000u);
        pa += w0*a0v.x + w1*a0v.y + w2*a0v.z + w3*a0v.w
            + w4*a1v.x + w5*a1v.y + w6*a1v.z + w7*a1v.w;
        pb += w0*b0v.x + w1*b0v.y + w2*b0v.z + w3*b0v.w
            + w4*b1v.x + w5*b1v.y + w6*b1v.z + w7*b1v.w;
      }
      pa += __shfl_xor(pa, 1, 64); pa += __shfl_xor(pa, 2, 64);
      pa += __shfl_xor(pa, 4, 64); pa += __shfl_xor(pa, 8, 64);
      pb += __shfl_xor(pb, 1, 64); pb += __shfl_xor(pb, 2, 64);
      pb += __shfl_xor(pb, 4, 64); pb += __shfl_xor(pb, 8, 64);
      if (cg == 0) {
        const float q0 = ((r == a0) ? 0.f : __expf(pa)) * dia0;
        const float q1 = ((r == a1) ? 0.f : __expf(pb)) * dia1;
        const float di = dinv_s[r];
        const float vr = vn * sqd_s[r];                      // v[r]
        const float w0n = ALPHA * (di * q0 - vr * s0);
        const float w1n = ALPHA * (di * q1 - vr * s1);
        float2 o;
        o.x = ((r == a0) ? 1.f : 0.f) + w0n + c99 * s0 * vr;
        o.y = ((r == a1) ? 1.f : 0.f) + w1n + c99 * s1 * vr;
        ob[r] = o;
      }
    }
  }
}

// ==========================================================================
extern "C" void kernel_launch(void* const* d_in, const int* in_sizes, int n_in,
                              void* d_out, int out_size, void* d_ws, size_t ws_size,
                              hipStream_t stream) {
  const float* F = (const float*)d_in[0];   // [B,K,D]
  const float* Q = (const float*)d_in[1];   // [B,D]
  float* out = (float*)d_out;               // [B,K,2]
  const int B = 128;

  __bf16* Fbf = (__bf16*)d_ws;                           // B*K*D bf16 (33.5 MB)
  float* Dgp  = (float*)(Fbf + (size_t)B * K * D);       // 4*B*K (partial degrees)
  float* simb = Dgp + (size_t)4 * B * K;                 // B*K
  u64*   p0   = (u64*)(simb + (size_t)B * K);            // B*8
  u64*   p1   = p0 + (size_t)B * 8;                      // B*4
  unsigned int* flags = (unsigned int*)(p1 + (size_t)B * 4);  // 3*128 slots, 64B stride

  hipMemsetAsync(flags, 0, 3 * 128 * 16 * sizeof(unsigned int), stream);
  pipe_kernel<<<3840, 256, 0, stream>>>(F, Q, Fbf, simb, p0, p1, Dgp, out, flags);
}

// Round 7
// 157.933 us; speedup vs baseline: 2.5055x; 2.3543x over previous
//
#include <hip/hip_runtime.h>
#include <math.h>

static constexpr int K = 512;
static constexpr int D = 256;
static constexpr float ALPHA = 0.99f;
static constexpr float EPSF  = 2.2204460492503131e-16f;

typedef __bf16 bf16x8 __attribute__((ext_vector_type(8)));
typedef float floatx4 __attribute__((ext_vector_type(4)));
typedef unsigned long long u64;

// ordered-float encoding: monotone map float -> u32 (smaller float => smaller u32)
__device__ __forceinline__ unsigned int f2o(float f) {
  unsigned int u = __float_as_uint(f);
  return (u & 0x80000000u) ? ~u : (u | 0x80000000u);
}

__device__ __forceinline__ u64 umin64(u64 a, u64 b) { return a < b ? a : b; }

// ====== sim1: sim = F.q, per-block partial argmin; ALSO emits bf16 F ======
// grid (8, B): block covers 64 rows; partial best -> p0[b*8 + bx]
__global__ __launch_bounds__(256) void sim1_kernel(
    const float* __restrict__ F, const float* __restrict__ Q,
    __bf16* __restrict__ Fbf, float* __restrict__ simbuf, u64* __restrict__ p0)
{
  const int b = blockIdx.y;
  const int r0 = blockIdx.x * 64;
  const float* Fb = F + (size_t)b * (K * D);
  __bf16* Fbb = Fbf + (size_t)b * (K * D);
  __shared__ __align__(16) float qs[D];
  __shared__ u64 wred[4];
  const int t = threadIdx.x;
  const int wave = t >> 6, lane = t & 63;
  const int sub = lane >> 4, cg = lane & 15;
  qs[t] = Q[(size_t)b * D + t];
  __syncthreads();

  u64 best = ~0ULL;
  #pragma unroll
  for (int pass = 0; pass < 4; ++pass) {
    const int r = r0 + pass * 16 + wave * 4 + sub;
    const float* fr = Fb + (size_t)r * D;
    float p = 0.f;
    #pragma unroll
    for (int q = 0; q < 2; ++q) {
      const int c = q * 128 + cg * 8;
      const float4 f0 = *(const float4*)(fr + c);
      const float4 f1 = *(const float4*)(fr + c + 4);
      const float4 q0 = *(const float4*)(qs + c);
      const float4 q1 = *(const float4*)(qs + c + 4);
      p += f0.x*q0.x + f0.y*q0.y + f0.z*q0.z + f0.w*q0.w
         + f1.x*q1.x + f1.y*q1.y + f1.z*q1.z + f1.w*q1.w;
      bf16x8 h;
      h[0] = (__bf16)f0.x; h[1] = (__bf16)f0.y; h[2] = (__bf16)f0.z; h[3] = (__bf16)f0.w;
      h[4] = (__bf16)f1.x; h[5] = (__bf16)f1.y; h[6] = (__bf16)f1.z; h[7] = (__bf16)f1.w;
      *(bf16x8*)(Fbb + (size_t)r * D + c) = h;
    }
    p += __shfl_xor(p, 1, 64); p += __shfl_xor(p, 2, 64);
    p += __shfl_xor(p, 4, 64); p += __shfl_xor(p, 8, 64);
    if (cg == 0) {
      simbuf[(size_t)b * K + r] = p;
      best = umin64(best, ((u64)f2o(p) << 32) | (unsigned int)r);
    }
  }
  best = umin64(best, __shfl_xor(best, 16, 64));
  best = umin64(best, __shfl_xor(best, 32, 64));
  if (lane == 0) wred[wave] = best;
  __syncthreads();
  if (t == 0)
    p0[b * 8 + blockIdx.x] =
        umin64(umin64(wred[0], wred[1]), umin64(wred[2], wred[3]));
}

// ====== fused: blocks <1280 = lower-tri gram tiles (bf16 MFMA); rest = sim2 ======
// gram staging is register-prefetched: next K-step's global loads issue right
// after the post-store barrier and their L3 latency hides under MFMA+ds_read.
__global__ __launch_bounds__(256, 4) void fused_kernel(
    const float* __restrict__ F, const __bf16* __restrict__ Fbf,
    const float* __restrict__ simbuf, const u64* __restrict__ p0,
    u64* __restrict__ p1, float* __restrict__ Dgp)
{
  __shared__ __align__(16) unsigned char smem[36864];
  const int id = blockIdx.x;
  const int t = threadIdx.x;
  const int wave = t >> 6, lane = t & 63;
  const int quad = lane >> 4, l15 = lane & 15;

  if (id < 1280) {
    // ---------------- gram tile: 128 x 128 ----------------
    const int b = id & 127;
    const int tid = id >> 7;                 // 0..9
    static constexpr int TI[10] = {0,1,1,2,2,2,3,3,3,3};
    static constexpr int TJ[10] = {0,0,1,0,1,2,0,1,2,3};
    const int ti = TI[tid], tj = TJ[tid];
    const int r0 = ti * 128, c0 = tj * 128;
    const bool diag = (ti == tj);
    const __bf16* Fb = Fbf + (size_t)b * (K * D);
    __bf16 (*Asb)[72] = (__bf16(*)[72])smem;            // 128 x 72 bf16
    __bf16 (*Bsb)[72] = diag ? Asb : (__bf16(*)[72])(smem + 18432);
    const int srow = t >> 1, skh = (t & 1) * 32;
    const __bf16* srcA = Fb + (size_t)(r0 + srow) * D + skh;
    const __bf16* srcB = Fb + (size_t)(c0 + srow) * D + skh;

    // prologue: prefetch K-step 0 into registers
    uint4 ra0, ra1, ra2, ra3;
    uint4 rb0{}, rb1{}, rb2{}, rb3{};
    ra0 = *(const uint4*)(srcA +  0);
    ra1 = *(const uint4*)(srcA +  8);
    ra2 = *(const uint4*)(srcA + 16);
    ra3 = *(const uint4*)(srcA + 24);
    if (!diag) {
      rb0 = *(const uint4*)(srcB +  0);
      rb1 = *(const uint4*)(srcB +  8);
      rb2 = *(const uint4*)(srcB + 16);
      rb3 = *(const uint4*)(srcB + 24);
    }

    floatx4 acc[2][8];
    #pragma unroll
    for (int i = 0; i < 2; ++i)
      #pragma unroll
      for (int j = 0; j < 8; ++j) acc[i][j] = (floatx4){0.f, 0.f, 0.f, 0.f};

    for (int kk = 0; kk < D; kk += 64) {
      __syncthreads();                       // LDS free (previous MFMA done)
      *(uint4*)&Asb[srow][skh +  0] = ra0;
      *(uint4*)&Asb[srow][skh +  8] = ra1;
      *(uint4*)&Asb[srow][skh + 16] = ra2;
      *(uint4*)&Asb[srow][skh + 24] = ra3;
      if (!diag) {
        *(uint4*)&Bsb[srow][skh +  0] = rb0;
        *(uint4*)&Bsb[srow][skh +  8] = rb1;
        *(uint4*)&Bsb[srow][skh + 16] = rb2;
        *(uint4*)&Bsb[srow][skh + 24] = rb3;
      }
      __syncthreads();
      if (kk + 64 < D) {                     // issue next K-step loads (hide L3 latency)
        const int o = kk + 64;
        ra0 = *(const uint4*)(srcA + o +  0);
        ra1 = *(const uint4*)(srcA + o +  8);
        ra2 = *(const uint4*)(srcA + o + 16);
        ra3 = *(const uint4*)(srcA + o + 24);
        if (!diag) {
          rb0 = *(const uint4*)(srcB + o +  0);
          rb1 = *(const uint4*)(srcB + o +  8);
          rb2 = *(const uint4*)(srcB + o + 16);
          rb3 = *(const uint4*)(srcB + o + 24);
        }
      }
      #pragma unroll
      for (int k2 = 0; k2 < 64; k2 += 32) {
        bf16x8 af[2], bf[8];
        #pragma unroll
        for (int tm = 0; tm < 2; ++tm)
          af[tm] = *(bf16x8*)&Asb[wave * 32 + tm * 16 + l15][k2 + quad * 8];
        #pragma unroll
        for (int tn = 0; tn < 8; ++tn)
          bf[tn] = *(bf16x8*)&Bsb[tn * 16 + l15][k2 + quad * 8];
        #pragma unroll
        for (int tm = 0; tm < 2; ++tm)
          #pragma unroll
          for (int tn = 0; tn < 8; ++tn)
            acc[tm][tn] = __builtin_amdgcn_mfma_f32_16x16x32_bf16(af[tm], bf[tn], acc[tm][tn], 0, 0, 0);
      }
    }

    // epilogue: exp (+zero diag on diag tiles), row sums + col sums
    float rs[8] = {0.f};
    float cs[8] = {0.f};
    #pragma unroll
    for (int tm = 0; tm < 2; ++tm) {
      const int lrb = wave * 32 + tm * 16 + quad * 4;
      #pragma unroll
      for (int tn = 0; tn < 8; ++tn) {
        const int lc = tn * 16 + l15;
        #pragma unroll
        for (int r = 0; r < 4; ++r) {
          float wv = __expf(acc[tm][tn][r]);
          if (diag && (lrb + r) == lc) wv = 0.f;
          rs[tm * 4 + r] += wv;
          cs[tn] += wv;
        }
      }
    }
    // row sums -> slot tj
    #pragma unroll
    for (int s = 0; s < 8; ++s) {
      float v = rs[s];
      v += __shfl_xor(v, 1, 64); v += __shfl_xor(v, 2, 64);
      v += __shfl_xor(v, 4, 64); v += __shfl_xor(v, 8, 64);
      if (l15 == 0) {
        const int r = r0 + wave * 32 + (s >> 2) * 16 + quad * 4 + (s & 3);
        Dgp[(size_t)tj * (128 * K) + (size_t)b * K + r] = v;
      }
    }
    // col sums -> slot ti (off-diag tiles only)
    if (!diag) {
      #pragma unroll
      for (int tn = 0; tn < 8; ++tn) {
        cs[tn] += __shfl_xor(cs[tn], 16, 64);
        cs[tn] += __shfl_xor(cs[tn], 32, 64);
      }
      __syncthreads();                       // done with Asb/Bsb
      float* csum = (float*)smem;            // 4 x 128 floats
      if (lane < 16) {
        #pragma unroll
        for (int tn = 0; tn < 8; ++tn)
          csum[wave * 128 + tn * 16 + l15] = cs[tn];
      }
      __syncthreads();
      if (t < 128) {
        const float s = csum[t] + csum[128 + t] + csum[256 + t] + csum[384 + t];
        Dgp[(size_t)ti * (128 * K) + (size_t)b * K + c0 + t] = s;
      }
    }
  } else {
    // ---------------- sim2 quarter (fp32-exact) ----------------
    const int id2 = id - 1280;
    const int b = id2 & 127, s = id2 >> 7;
    const int r0 = s * 128;
    const float* Fb = F + (size_t)b * (K * D);
    float* qs = (float*)smem;
    u64* wred = (u64*)(smem + 1024);
    const int sub = lane >> 4, cg = lane & 15;

    u64 e0 = p0[b * 8];
    #pragma unroll
    for (int i = 1; i < 8; ++i) e0 = umin64(e0, p0[b * 8 + i]);
    const int a0 = (int)(e0 & 0xffffffffu);

    qs[t] = Fb[(size_t)a0 * D + t];
    __syncthreads();

    u64 best = ~0ULL;
    #pragma unroll
    for (int pass = 0; pass < 8; ++pass) {
      const int r = r0 + pass * 16 + wave * 4 + sub;
      const float* fr = Fb + (size_t)r * D;
      float p = 0.f;
      #pragma unroll
      for (int q = 0; q < 2; ++q) {
        const int c = q * 128 + cg * 8;
        const float4 f0 = *(const float4*)(fr + c);
        const float4 f1 = *(const float4*)(fr + c + 4);
        const float4 q0 = *(const float4*)(qs + c);
        const float4 q1 = *(const float4*)(qs + c + 4);
        p += f0.x*q0.x + f0.y*q0.y + f0.z*q0.z + f0.w*q0.w
           + f1.x*q1.x + f1.y*q1.y + f1.z*q1.z + f1.w*q1.w;
      }
      p += __shfl_xor(p, 1, 64); p += __shfl_xor(p, 2, 64);
      p += __shfl_xor(p, 4, 64); p += __shfl_xor(p, 8, 64);
      if (cg == 0) {
        const float m = fmaxf(simbuf[(size_t)b * K + r], p);
        best = umin64(best, ((u64)f2o(m) << 32) | (unsigned int)r);
      }
    }
    best = umin64(best, __shfl_xor(best, 16, 64));
    best = umin64(best, __shfl_xor(best, 32, 64));
    if (lane == 0) wred[wave] = best;
    __syncthreads();
    if (t == 0)
      p1[b * 4 + s] =
          umin64(umin64(wred[0], wred[1]), umin64(wred[2], wred[3]));
  }
}

// ===== final: out = y + alpha*R*y + alpha/(1-alpha) * v * (v.y)  (NIT=1) =====
// degrees = sum of 4 partial slots; anchor-column GEMVs read bf16 F.
__global__ __launch_bounds__(256) void final_kernel(
    const float* __restrict__ F, const __bf16* __restrict__ Fbf,
    const float* __restrict__ Dgp, const u64* __restrict__ p0,
    const u64* __restrict__ p1, float* __restrict__ out)
{
  const int b = blockIdx.y;
  const int r0 = blockIdx.x * 128;
  const float* Fb = F + (size_t)b * (K * D);
  const __bf16* Fbb = Fbf + (size_t)b * (K * D);
  __shared__ __align__(16) float qa[D], qb[D];
  __shared__ float dinv_s[K], sqd_s[K];
  __shared__ float red[4];
  const int t = threadIdx.x;
  const int wave = t >> 6, lane = t & 63;
  const int sub = lane >> 4, cg = lane & 15;

  u64 e0 = p0[b * 8];
  #pragma unroll
  for (int i = 1; i < 8; ++i) e0 = umin64(e0, p0[b * 8 + i]);
  u64 e1 = p1[b * 4];
  #pragma unroll
  for (int i = 1; i < 4; ++i) e1 = umin64(e1, p1[b * 4 + i]);
  const int a0 = (int)(e0 & 0xffffffffu);
  const int a1 = (int)(e1 & 0xffffffffu);

  qa[t] = Fb[(size_t)a0 * D + t];
  qb[t] = Fb[(size_t)a1 * D + t];
  float dsum = 0.f;
  for (int k = t; k < K; k += 256) {
    const size_t o = (size_t)b * K + k;
    const float d = Dgp[o] + Dgp[(size_t)128 * K + o]
                  + Dgp[(size_t)2 * 128 * K + o] + Dgp[(size_t)3 * 128 * K + o];
    dinv_s[k] = 1.0f / sqrtf(d + EPSF);
    sqd_s[k] = sqrtf(d);
    dsum += d;
  }
  #pragma unroll
  for (int off = 32; off >= 1; off >>= 1) dsum += __shfl_down(dsum, off, 64);
  if (lane == 0) red[wave] = dsum;
  __syncthreads();
  const float vn = 1.0f / sqrtf(red[0] + red[1] + red[2] + red[3]);
  const float s0 = vn * sqd_s[a0], s1 = vn * sqd_s[a1];   // v[a0], v[a1]
  const float dia0 = dinv_s[a0], dia1 = dinv_s[a1];
  const float c99 = ALPHA / (1.0f - ALPHA);

  float2* ob = (float2*)(out + (size_t)b * K * 2);

  #pragma unroll
  for (int pass = 0; pass < 8; ++pass) {
    const int r = r0 + pass * 16 + wave * 4 + sub;
    const __bf16* fr = Fbb + (size_t)r * D;
    float pa = 0.f, pb = 0.f;
    #pragma unroll
    for (int q = 0; q < 2; ++q) {
      const int c = q * 128 + cg * 8;
      const uint4 wv = *(const uint4*)(fr + c);
      const float4 a0v = *(const float4*)(qa + c);
      const float4 a1v = *(const float4*)(qa + c + 4);
      const float4 b0v = *(const float4*)(qb + c);
      const float4 b1v = *(const float4*)(qb + c + 4);
      const float w0 = __uint_as_float(wv.x << 16);
      const float w1 = __uint_as_float(wv.x & 0xffff0000u);
      const float w2 = __uint_as_float(wv.y << 16);
      const float w3 = __uint_as_float(wv.y & 0xffff0000u);
      const float w4 = __uint_as_float(wv.z << 16);
      const float w5 = __uint_as_float(wv.z & 0xffff0000u);
      const float w6 = __uint_as_float(wv.w << 16);
      const float w7 = __uint_as_float(wv.w & 0xffff0000u);
      pa += w0*a0v.x + w1*a0v.y + w2*a0v.z + w3*a0v.w
          + w4*a1v.x + w5*a1v.y + w6*a1v.z + w7*a1v.w;
      pb += w0*b0v.x + w1*b0v.y + w2*b0v.z + w3*b0v.w
          + w4*b1v.x + w5*b1v.y + w6*b1v.z + w7*b1v.w;
    }
    pa += __shfl_xor(pa, 1, 64); pa += __shfl_xor(pa, 2, 64);
    pa += __shfl_xor(pa, 4, 64); pa += __shfl_xor(pa, 8, 64);
    pb += __shfl_xor(pb, 1, 64); pb += __shfl_xor(pb, 2, 64);
    pb += __shfl_xor(pb, 4, 64); pb += __shfl_xor(pb, 8, 64);
    if (cg == 0) {
      const float q0 = ((r == a0) ? 0.f : __expf(pa)) * dia0;
      const float q1 = ((r == a1) ? 0.f : __expf(pb)) * dia1;
      const float di = dinv_s[r];
      const float vr = vn * sqd_s[r];                      // v[r]
      const float w0n = ALPHA * (di * q0 - vr * s0);
      const float w1n = ALPHA * (di * q1 - vr * s1);
      float2 o;
      o.x = ((r == a0) ? 1.f : 0.f) + w0n + c99 * s0 * vr;
      o.y = ((r == a1) ? 1.f : 0.f) + w1n + c99 * s1 * vr;
      ob[r] = o;
    }
  }
}

// ==========================================================================
extern "C" void kernel_launch(void* const* d_in, const int* in_sizes, int n_in,
                              void* d_out, int out_size, void* d_ws, size_t ws_size,
                              hipStream_t stream) {
  const float* F = (const float*)d_in[0];   // [B,K,D]
  const float* Q = (const float*)d_in[1];   // [B,D]
  float* out = (float*)d_out;               // [B,K,2]
  const int B = in_sizes[1] / D;            // 128

  __bf16* Fbf = (__bf16*)d_ws;                           // B*K*D bf16 (33.5 MB)
  float* Dgp  = (float*)(Fbf + (size_t)B * K * D);       // 4*B*K (partial degrees)
  float* simb = Dgp + (size_t)4 * B * K;                 // B*K
  u64*   p0   = (u64*)(simb + (size_t)B * K);            // B*8
  u64*   p1   = p0 + (size_t)B * 8;                      // B*4

  sim1_kernel<<<dim3(8, B), 256, 0, stream>>>(F, Q, Fbf, simb, p0);
  fused_kernel<<<1792, 256, 0, stream>>>(F, Fbf, simb, p0, p1, Dgp);
  final_kernel<<<dim3(4, B), 256, 0, stream>>>(F, Fbf, Dgp, p0, p1, out);
}

// Round 8
// 138.195 us; speedup vs baseline: 2.8633x; 1.1428x over previous
//
#include <hip/hip_runtime.h>
#include <math.h>

static constexpr int K = 512;
static constexpr int D = 256;
static constexpr float ALPHA = 0.99f;
static constexpr float EPSF  = 2.2204460492503131e-16f;

typedef __bf16 bf16x8 __attribute__((ext_vector_type(8)));
typedef float floatx4 __attribute__((ext_vector_type(4)));
typedef unsigned long long u64;

// ordered-float encoding: monotone map float -> u32 (smaller float => smaller u32)
__device__ __forceinline__ unsigned int f2o(float f) {
  unsigned int u = __float_as_uint(f);
  return (u & 0x80000000u) ? ~u : (u | 0x80000000u);
}

__device__ __forceinline__ u64 umin64(u64 a, u64 b) { return a < b ? a : b; }

// ====== sim1: sim = F.q, per-block partial argmin; ALSO emits bf16 F ======
// grid (8, B): block covers 64 rows; partial best -> p0[b*8 + bx]
__global__ __launch_bounds__(256) void sim1_kernel(
    const float* __restrict__ F, const float* __restrict__ Q,
    __bf16* __restrict__ Fbf, float* __restrict__ simbuf, u64* __restrict__ p0)
{
  const int b = blockIdx.y;
  const int r0 = blockIdx.x * 64;
  const float* Fb = F + (size_t)b * (K * D);
  __bf16* Fbb = Fbf + (size_t)b * (K * D);
  __shared__ __align__(16) float qs[D];
  __shared__ u64 wred[4];
  const int t = threadIdx.x;
  const int wave = t >> 6, lane = t & 63;
  const int sub = lane >> 4, cg = lane & 15;
  qs[t] = Q[(size_t)b * D + t];
  __syncthreads();

  u64 best = ~0ULL;
  #pragma unroll
  for (int pass = 0; pass < 4; ++pass) {
    const int r = r0 + pass * 16 + wave * 4 + sub;
    const float* fr = Fb + (size_t)r * D;
    float p = 0.f;
    #pragma unroll
    for (int q = 0; q < 2; ++q) {
      const int c = q * 128 + cg * 8;
      const float4 f0 = *(const float4*)(fr + c);
      const float4 f1 = *(const float4*)(fr + c + 4);
      const float4 q0 = *(const float4*)(qs + c);
      const float4 q1 = *(const float4*)(qs + c + 4);
      p += f0.x*q0.x + f0.y*q0.y + f0.z*q0.z + f0.w*q0.w
         + f1.x*q1.x + f1.y*q1.y + f1.z*q1.z + f1.w*q1.w;
      bf16x8 h;
      h[0] = (__bf16)f0.x; h[1] = (__bf16)f0.y; h[2] = (__bf16)f0.z; h[3] = (__bf16)f0.w;
      h[4] = (__bf16)f1.x; h[5] = (__bf16)f1.y; h[6] = (__bf16)f1.z; h[7] = (__bf16)f1.w;
      *(bf16x8*)(Fbb + (size_t)r * D + c) = h;
    }
    p += __shfl_xor(p, 1, 64); p += __shfl_xor(p, 2, 64);
    p += __shfl_xor(p, 4, 64); p += __shfl_xor(p, 8, 64);
    if (cg == 0) {
      simbuf[(size_t)b * K + r] = p;
      best = umin64(best, ((u64)f2o(p) << 32) | (unsigned int)r);
    }
  }
  best = umin64(best, __shfl_xor(best, 16, 64));
  best = umin64(best, __shfl_xor(best, 32, 64));
  if (lane == 0) wred[wave] = best;
  __syncthreads();
  if (t == 0)
    p0[b * 8 + blockIdx.x] =
        umin64(umin64(wred[0], wred[1]), umin64(wred[2], wred[3]));
}

// ====== fused: blocks <512 = sim2 quarters (HBM-heavy, dispatched first so their
// F-streams start immediately); blocks 512..1791 = lower-tri gram tiles (bf16 MFMA) ======
__global__ __launch_bounds__(256) void fused_kernel(
    const float* __restrict__ F, const __bf16* __restrict__ Fbf,
    const float* __restrict__ simbuf, const u64* __restrict__ p0,
    u64* __restrict__ p1, float* __restrict__ Dgp)
{
  __shared__ __align__(16) unsigned char smem[36864];
  const int id = blockIdx.x;
  const int t = threadIdx.x;
  const int wave = t >> 6, lane = t & 63;
  const int quad = lane >> 4, l15 = lane & 15;

  if (id >= 512) {
    // ---------------- gram tile: 128 x 128 ----------------
    const int T = id - 512;
    const int b = T & 127;
    const int tid = T >> 7;                 // 0..9
    static constexpr int TI[10] = {0,1,1,2,2,2,3,3,3,3};
    static constexpr int TJ[10] = {0,0,1,0,1,2,0,1,2,3};
    const int ti = TI[tid], tj = TJ[tid];
    const int r0 = ti * 128, c0 = tj * 128;
    const bool diag = (ti == tj);
    const __bf16* Fb = Fbf + (size_t)b * (K * D);
    __bf16 (*Asb)[72] = (__bf16(*)[72])smem;            // 128 x 72 bf16
    __bf16 (*Bsb)[72] = diag ? Asb : (__bf16(*)[72])(smem + 18432);
    const int srow = t >> 1, skh = (t & 1) * 32;

    floatx4 acc[2][8];
    #pragma unroll
    for (int i = 0; i < 2; ++i)
      #pragma unroll
      for (int j = 0; j < 8; ++j) acc[i][j] = (floatx4){0.f, 0.f, 0.f, 0.f};

    for (int kk = 0; kk < D; kk += 64) {
      __syncthreads();
      {
        const __bf16* sa = Fb + (size_t)(r0 + srow) * D + kk + skh;
        *(uint4*)&Asb[srow][skh +  0] = *(const uint4*)(sa +  0);
        *(uint4*)&Asb[srow][skh +  8] = *(const uint4*)(sa +  8);
        *(uint4*)&Asb[srow][skh + 16] = *(const uint4*)(sa + 16);
        *(uint4*)&Asb[srow][skh + 24] = *(const uint4*)(sa + 24);
        if (!diag) {
          const __bf16* sb = Fb + (size_t)(c0 + srow) * D + kk + skh;
          *(uint4*)&Bsb[srow][skh +  0] = *(const uint4*)(sb +  0);
          *(uint4*)&Bsb[srow][skh +  8] = *(const uint4*)(sb +  8);
          *(uint4*)&Bsb[srow][skh + 16] = *(const uint4*)(sb + 16);
          *(uint4*)&Bsb[srow][skh + 24] = *(const uint4*)(sb + 24);
        }
      }
      __syncthreads();
      #pragma unroll
      for (int k2 = 0; k2 < 64; k2 += 32) {
        bf16x8 af[2], bf[8];
        #pragma unroll
        for (int tm = 0; tm < 2; ++tm)
          af[tm] = *(bf16x8*)&Asb[wave * 32 + tm * 16 + l15][k2 + quad * 8];
        #pragma unroll
        for (int tn = 0; tn < 8; ++tn)
          bf[tn] = *(bf16x8*)&Bsb[tn * 16 + l15][k2 + quad * 8];
        #pragma unroll
        for (int tm = 0; tm < 2; ++tm)
          #pragma unroll
          for (int tn = 0; tn < 8; ++tn)
            acc[tm][tn] = __builtin_amdgcn_mfma_f32_16x16x32_bf16(af[tm], bf[tn], acc[tm][tn], 0, 0, 0);
      }
    }

    // epilogue: exp (+zero diag on diag tiles), row sums + col sums
    float rs[8] = {0.f};
    float cs[8] = {0.f};
    #pragma unroll
    for (int tm = 0; tm < 2; ++tm) {
      const int lrb = wave * 32 + tm * 16 + quad * 4;
      #pragma unroll
      for (int tn = 0; tn < 8; ++tn) {
        const int lc = tn * 16 + l15;
        #pragma unroll
        for (int r = 0; r < 4; ++r) {
          float wv = __expf(acc[tm][tn][r]);
          if (diag && (lrb + r) == lc) wv = 0.f;
          rs[tm * 4 + r] += wv;
          cs[tn] += wv;
        }
      }
    }
    // row sums -> slot tj
    #pragma unroll
    for (int s = 0; s < 8; ++s) {
      float v = rs[s];
      v += __shfl_xor(v, 1, 64); v += __shfl_xor(v, 2, 64);
      v += __shfl_xor(v, 4, 64); v += __shfl_xor(v, 8, 64);
      if (l15 == 0) {
        const int r = r0 + wave * 32 + (s >> 2) * 16 + quad * 4 + (s & 3);
        Dgp[(size_t)tj * (128 * K) + (size_t)b * K + r] = v;
      }
    }
    // col sums -> slot ti (off-diag tiles only)
    if (!diag) {
      #pragma unroll
      for (int tn = 0; tn < 8; ++tn) {
        cs[tn] += __shfl_xor(cs[tn], 16, 64);
        cs[tn] += __shfl_xor(cs[tn], 32, 64);
      }
      __syncthreads();                       // done with Asb/Bsb
      float* csum = (float*)smem;            // 4 x 128 floats
      if (lane < 16) {
        #pragma unroll
        for (int tn = 0; tn < 8; ++tn)
          csum[wave * 128 + tn * 16 + l15] = cs[tn];
      }
      __syncthreads();
      if (t < 128) {
        const float s = csum[t] + csum[128 + t] + csum[256 + t] + csum[384 + t];
        Dgp[(size_t)ti * (128 * K) + (size_t)b * K + c0 + t] = s;
      }
    }
  } else {
    // ---------------- sim2 quarter (fp32-exact), ids 0..511 ----------------
    const int b = id & 127, s = id >> 7;
    const int r0 = s * 128;
    const float* Fb = F + (size_t)b * (K * D);
    float* qs = (float*)smem;
    u64* wred = (u64*)(smem + 1024);
    const int sub = lane >> 4, cg = lane & 15;

    u64 e0 = p0[b * 8];
    #pragma unroll
    for (int i = 1; i < 8; ++i) e0 = umin64(e0, p0[b * 8 + i]);
    const int a0 = (int)(e0 & 0xffffffffu);

    qs[t] = Fb[(size_t)a0 * D + t];
    __syncthreads();

    u64 best = ~0ULL;
    #pragma unroll
    for (int pass = 0; pass < 8; ++pass) {
      const int r = r0 + pass * 16 + wave * 4 + sub;
      const float* fr = Fb + (size_t)r * D;
      float p = 0.f;
      #pragma unroll
      for (int q = 0; q < 2; ++q) {
        const int c = q * 128 + cg * 8;
        const float4 f0 = *(const float4*)(fr + c);
        const float4 f1 = *(const float4*)(fr + c + 4);
        const float4 q0 = *(const float4*)(qs + c);
        const float4 q1 = *(const float4*)(qs + c + 4);
        p += f0.x*q0.x + f0.y*q0.y + f0.z*q0.z + f0.w*q0.w
           + f1.x*q1.x + f1.y*q1.y + f1.z*q1.z + f1.w*q1.w;
      }
      p += __shfl_xor(p, 1, 64); p += __shfl_xor(p, 2, 64);
      p += __shfl_xor(p, 4, 64); p += __shfl_xor(p, 8, 64);
      if (cg == 0) {
        const float m = fmaxf(simbuf[(size_t)b * K + r], p);
        best = umin64(best, ((u64)f2o(m) << 32) | (unsigned int)r);
      }
    }
    best = umin64(best, __shfl_xor(best, 16, 64));
    best = umin64(best, __shfl_xor(best, 32, 64));
    if (lane == 0) wred[wave] = best;
    __syncthreads();
    if (t == 0)
      p1[b * 4 + s] =
          umin64(umin64(wred[0], wred[1]), umin64(wred[2], wred[3]));
  }
}

// ===== final: out = y + alpha*R*y + alpha/(1-alpha) * v * (v.y)  (NIT=1) =====
// degrees = sum of 4 partial slots; anchor-column GEMVs read bf16 F.
__global__ __launch_bounds__(256) void final_kernel(
    const float* __restrict__ F, const __bf16* __restrict__ Fbf,
    const float* __restrict__ Dgp, const u64* __restrict__ p0,
    const u64* __restrict__ p1, float* __restrict__ out)
{
  const int b = blockIdx.y;
  const int r0 = blockIdx.x * 128;
  const float* Fb = F + (size_t)b * (K * D);
  const __bf16* Fbb = Fbf + (size_t)b * (K * D);
  __shared__ __align__(16) float qa[D], qb[D];
  __shared__ float dinv_s[K], sqd_s[K];
  __shared__ float red[4];
  const int t = threadIdx.x;
  const int wave = t >> 6, lane = t & 63;
  const int sub = lane >> 4, cg = lane & 15;

  u64 e0 = p0[b * 8];
  #pragma unroll
  for (int i = 1; i < 8; ++i) e0 = umin64(e0, p0[b * 8 + i]);
  u64 e1 = p1[b * 4];
  #pragma unroll
  for (int i = 1; i < 4; ++i) e1 = umin64(e1, p1[b * 4 + i]);
  const int a0 = (int)(e0 & 0xffffffffu);
  const int a1 = (int)(e1 & 0xffffffffu);

  qa[t] = Fb[(size_t)a0 * D + t];
  qb[t] = Fb[(size_t)a1 * D + t];
  float dsum = 0.f;
  for (int k = t; k < K; k += 256) {
    const size_t o = (size_t)b * K + k;
    const float d = Dgp[o] + Dgp[(size_t)128 * K + o]
                  + Dgp[(size_t)2 * 128 * K + o] + Dgp[(size_t)3 * 128 * K + o];
    dinv_s[k] = 1.0f / sqrtf(d + EPSF);
    sqd_s[k] = sqrtf(d);
    dsum += d;
  }
  #pragma unroll
  for (int off = 32; off >= 1; off >>= 1) dsum += __shfl_down(dsum, off, 64);
  if (lane == 0) red[wave] = dsum;
  __syncthreads();
  const float vn = 1.0f / sqrtf(red[0] + red[1] + red[2] + red[3]);
  const float s0 = vn * sqd_s[a0], s1 = vn * sqd_s[a1];   // v[a0], v[a1]
  const float dia0 = dinv_s[a0], dia1 = dinv_s[a1];
  const float c99 = ALPHA / (1.0f - ALPHA);

  float2* ob = (float2*)(out + (size_t)b * K * 2);

  #pragma unroll
  for (int pass = 0; pass < 8; ++pass) {
    const int r = r0 + pass * 16 + wave * 4 + sub;
    const __bf16* fr = Fbb + (size_t)r * D;
    float pa = 0.f, pb = 0.f;
    #pragma unroll
    for (int q = 0; q < 2; ++q) {
      const int c = q * 128 + cg * 8;
      const uint4 wv = *(const uint4*)(fr + c);
      const float4 a0v = *(const float4*)(qa + c);
      const float4 a1v = *(const float4*)(qa + c + 4);
      const float4 b0v = *(const float4*)(qb + c);
      const float4 b1v = *(const float4*)(qb + c + 4);
      const float w0 = __uint_as_float(wv.x << 16);
      const float w1 = __uint_as_float(wv.x & 0xffff0000u);
      const float w2 = __uint_as_float(wv.y << 16);
      const float w3 = __uint_as_float(wv.y & 0xffff0000u);
      const float w4 = __uint_as_float(wv.z << 16);
      const float w5 = __uint_as_float(wv.z & 0xffff0000u);
      const float w6 = __uint_as_float(wv.w << 16);
      const float w7 = __uint_as_float(wv.w & 0xffff0000u);
      pa += w0*a0v.x + w1*a0v.y + w2*a0v.z + w3*a0v.w
          + w4*a1v.x + w5*a1v.y + w6*a1v.z + w7*a1v.w;
      pb += w0*b0v.x + w1*b0v.y + w2*b0v.z + w3*b0v.w
          + w4*b1v.x + w5*b1v.y + w6*b1v.z + w7*b1v.w;
    }
    pa += __shfl_xor(pa, 1, 64); pa += __shfl_xor(pa, 2, 64);
    pa += __shfl_xor(pa, 4, 64); pa += __shfl_xor(pa, 8, 64);
    pb += __shfl_xor(pb, 1, 64); pb += __shfl_xor(pb, 2, 64);
    pb += __shfl_xor(pb, 4, 64); pb += __shfl_xor(pb, 8, 64);
    if (cg == 0) {
      const float q0 = ((r == a0) ? 0.f : __expf(pa)) * dia0;
      const float q1 = ((r == a1) ? 0.f : __expf(pb)) * dia1;
      const float di = dinv_s[r];
      const float vr = vn * sqd_s[r];                      // v[r]
      const float w0n = ALPHA * (di * q0 - vr * s0);
      const float w1n = ALPHA * (di * q1 - vr * s1);
      float2 o;
      o.x = ((r == a0) ? 1.f : 0.f) + w0n + c99 * s0 * vr;
      o.y = ((r == a1) ? 1.f : 0.f) + w1n + c99 * s1 * vr;
      ob[r] = o;
    }
  }
}

// ==========================================================================
extern "C" void kernel_launch(void* const* d_in, const int* in_sizes, int n_in,
                              void* d_out, int out_size, void* d_ws, size_t ws_size,
                              hipStream_t stream) {
  const float* F = (const float*)d_in[0];   // [B,K,D]
  const float* Q = (const float*)d_in[1];   // [B,D]
  float* out = (float*)d_out;               // [B,K,2]
  const int B = in_sizes[1] / D;            // 128

  __bf16* Fbf = (__bf16*)d_ws;                           // B*K*D bf16 (33.5 MB)
  float* Dgp  = (float*)(Fbf + (size_t)B * K * D);       // 4*B*K (partial degrees)
  float* simb = Dgp + (size_t)4 * B * K;                 // B*K
  u64*   p0   = (u64*)(simb + (size_t)B * K);            // B*8
  u64*   p1   = p0 + (size_t)B * 8;                      // B*4

  sim1_kernel<<<dim3(8, B), 256, 0, stream>>>(F, Q, Fbf, simb, p0);
  fused_kernel<<<1792, 256, 0, stream>>>(F, Fbf, simb, p0, p1, Dgp);
  final_kernel<<<dim3(4, B), 256, 0, stream>>>(F, Fbf, Dgp, p0, p1, out);
}